// Round 7
// baseline (1046.537 us; speedup 1.0000x reference)
//
#include <hip/hip_runtime.h>
#include <hip/hip_bf16.h>
#include <stdint.h>

#define N_NODES 262144
#define E_EDGES 4194304
#define EPAD    4194310            // E + 6
#define SRC_OFF 524288
#define DST_OFF (524288 + 4194310)
#define W_OFF   (524288 + 2 * 4194310)
#define NCHUNK  512                // partition chunks
#define EPC     (E_EDGES / NCHUNK) // 8192 edges per chunk
#define NBUCK   2048               // dst buckets
#define BSH     7                  // bucket = d >> 7 (128 nodes per bucket)

using bf16 = __hip_bfloat16;

__device__ __forceinline__ float b2f(unsigned int u) {
    union { unsigned int i; float f; } v; v.i = u << 16; return v.f;
}

// ---------------------------------------------------------------------------
// Pass 1: edge outputs (src/dst/w f32, verified r2-r6) + per-chunk bucket
// histogram -> counts[chunk][bucket] (plain stores, NO global atomics).
// ---------------------------------------------------------------------------
__global__ void __launch_bounds__(256) hist_kernel(const int* __restrict__ ei,
        float* __restrict__ out, uint32_t* __restrict__ counts) {
    __shared__ uint32_t cnt[NBUCK];
    int tid = threadIdx.x;
    for (int i = tid; i < NBUCK; i += 256) cnt[i] = 0;
    __syncthreads();
    int e0 = blockIdx.x * EPC;
    for (int i = 0; i < EPC; i += 256) {
        int e = e0 + i + tid;
        int s = ei[e], d = ei[E_EDGES + e];
        out[SRC_OFF + e] = (float)s;
        out[DST_OFF + e] = (float)d;
        out[W_OFF + e]   = (s < 32768 && d < 32768) ? 1.0f : 0.0f;
        atomicAdd(&cnt[d >> BSH], 1u);
    }
    if (blockIdx.x == 0 && tid < 6) {   // pad slots E..E+5
        int stage = tid >> 1;
        int m = 131072 >> stage;
        int s, d;
        if ((tid & 1) == 0) { s = m - 1; d = 0; } else { s = 0; d = m - 1; }
        int e = E_EDGES + tid;
        out[SRC_OFF + e] = (float)s;
        out[DST_OFF + e] = (float)d;
        out[W_OFF + e]   = (stage == 2) ? 1.0f : 0.0f;
    }
    __syncthreads();
    for (int i = tid; i < NBUCK; i += 256) counts[blockIdx.x * NBUCK + i] = cnt[i];
}

// ---------------------------------------------------------------------------
// Pass 2a: per-bucket column exclusive scan over chunks (in-place) + totals.
// ---------------------------------------------------------------------------
__global__ void __launch_bounds__(256) colscan_kernel(uint32_t* __restrict__ counts,
        uint32_t* __restrict__ tot) {
    __shared__ uint32_t sc[256];
    int b = blockIdx.x, t = threadIdx.x;
    uint32_t a0 = counts[(2 * t) * NBUCK + b];
    uint32_t a1 = counts[(2 * t + 1) * NBUCK + b];
    uint32_t p = a0 + a1;
    sc[t] = p; __syncthreads();
    for (int s = 1; s < 256; s <<= 1) {
        uint32_t x = (t >= s) ? sc[t - s] : 0u;
        __syncthreads();
        sc[t] += x;
        __syncthreads();
    }
    uint32_t excl = sc[t] - p;
    counts[(2 * t) * NBUCK + b]     = excl;
    counts[(2 * t + 1) * NBUCK + b] = excl + a0;
    if (t == 255) tot[b] = sc[255];
}

// Pass 2b: exclusive scan of bucket totals -> base[0..2048] (base[2048]=E).
__global__ void __launch_bounds__(256) base_kernel(const uint32_t* __restrict__ tot,
        uint32_t* __restrict__ base) {
    __shared__ uint32_t sc[256];
    int t = threadIdx.x;
    uint32_t v[8]; uint32_t p = 0;
#pragma unroll
    for (int j = 0; j < 8; ++j) { v[j] = tot[t * 8 + j]; p += v[j]; }
    sc[t] = p; __syncthreads();
    for (int s = 1; s < 256; s <<= 1) {
        uint32_t x = (t >= s) ? sc[t - s] : 0u;
        __syncthreads();
        sc[t] += x;
        __syncthreads();
    }
    uint32_t run = sc[t] - p;
#pragma unroll
    for (int j = 0; j < 8; ++j) { base[t * 8 + j] = run; run += v[j]; }
    if (t == 255) base[2048] = sc[255];
}

// ---------------------------------------------------------------------------
// Pass 3: place edges into dst-bucketed order (rank via LDS atomics only).
// ---------------------------------------------------------------------------
__global__ void __launch_bounds__(256) partition_kernel(const int* __restrict__ ei,
        const uint32_t* __restrict__ pref, const uint32_t* __restrict__ base,
        int2* __restrict__ part) {
    __shared__ uint32_t cnt[NBUCK];
    int tid = threadIdx.x;
    for (int i = tid; i < NBUCK; i += 256) cnt[i] = 0;
    __syncthreads();
    int e0 = blockIdx.x * EPC;
    const uint32_t* prow = pref + blockIdx.x * NBUCK;
    for (int i = 0; i < EPC; i += 256) {
        int e = e0 + i + tid;
        int s = ei[e], d = ei[E_EDGES + e];
        int bin = d >> BSH;
        uint32_t r = atomicAdd(&cnt[bin], 1u);
        part[base[bin] + prow[bin] + r] = make_int2(s, d);
    }
}

// ---------------------------------------------------------------------------
// Pass 4: exact degrees for all 3 stages from the partition (LDS histograms,
// each bucket owns its 128 nodes -> plain coalesced dinv writes).
// ---------------------------------------------------------------------------
__global__ void __launch_bounds__(256) degall_kernel(const int2* __restrict__ part,
        const uint32_t* __restrict__ base, float* __restrict__ dinv1,
        float* __restrict__ dinv2, float* __restrict__ dinv3) {
    __shared__ uint32_t c1[128], c2[128], c3[128];
    int b = blockIdx.x, tid = threadIdx.x;
    if (tid < 128) { c1[tid] = 0; c2[tid] = 0; c3[tid] = 0; }
    __syncthreads();
    uint32_t start = base[b], end = base[b + 1];
    for (uint32_t i = start + tid; i < end; i += 256) {
        int2 sd = part[i];
        int li = sd.y & 127;
        atomicAdd(&c1[li], 1u);
        if (b < 1024 && sd.x < 131072) atomicAdd(&c2[li], 1u);
        if (b < 512  && sd.x < 65536)  atomicAdd(&c3[li], 1u);
    }
    __syncthreads();
    if (tid == 0) {   // pad-edge degree contributions
        if (b == 0)    { c2[0] += 1; c3[0] += 1; }
        if (b == 1023) c2[127] += 1;
        if (b == 511)  c3[127] += 1;
    }
    __syncthreads();
    if (tid < 128) {
        int node = b * 128 + tid;
        dinv1[node] = rsqrtf((float)c1[tid] + 1.0f);
        if (b < 1024) dinv2[node] = rsqrtf((float)c2[tid] + 1.0f);
        if (b < 512)  dinv3[node] = rsqrtf((float)c3[tid] + 1.0f);
    }
}

// ---------------------------------------------------------------------------
// h = x @ W (bf16 out). Input f32 (stage 1) or bf16 (pooled stages).
// ---------------------------------------------------------------------------
template <int FOUT, bool IN_BF16>
__global__ void __launch_bounds__(256) xform_kernel(const void* __restrict__ xin_,
        const float* __restrict__ W, bf16* __restrict__ h) {
    constexpr int FIN = 32;
    constexpr int NPB = 256 / FOUT;
    __shared__ float sW[FIN * FOUT];
    __shared__ float sx[NPB * FIN];
    int tid = threadIdx.x;
    for (int i = tid; i < FIN * FOUT; i += 256) sW[i] = W[i];
    int node0 = blockIdx.x * NPB;
    if constexpr (IN_BF16) {
        const unsigned short* xin = (const unsigned short*)xin_;
        for (int i = tid; i < NPB * FIN; i += 256) sx[i] = b2f(xin[node0 * FIN + i]);
    } else {
        const float* xin = (const float*)xin_;
        for (int i = tid; i < NPB * FIN; i += 256) sx[i] = xin[node0 * FIN + i];
    }
    __syncthreads();
    int nl = tid / FOUT, j = tid % FOUT;
    float acc = 0.0f;
#pragma unroll
    for (int k = 0; k < FIN; ++k) acc += sx[nl * FIN + k] * sW[k * FOUT + j];
    h[(node0 + nl) * FOUT + j] = __float2bfloat16(acc);
}

// ---------------------------------------------------------------------------
// Fused aggregate + self-term + bias + relu + pool. One block per dst bucket
// (128 nodes, exclusively owned): LDS f32 accumulation, NO global atomics.
// Factored norm: out[d] = dinv[d]*SUM(dinv[s]*h[s]) + dinv[d]^2*h[d] + bias.
// ---------------------------------------------------------------------------
template <int FOUT, bool OUT_BF16>
__global__ void __launch_bounds__(256) agg_kernel(const int2* __restrict__ part,
        const uint32_t* __restrict__ base, const float* __restrict__ dinv,
        const bf16* __restrict__ h_, const float* __restrict__ bias,
        void* __restrict__ outp, int n, int sThresh, int pads) {
    constexpr int EPT = FOUT / 4;    // threads per edge (8 / 4)
    constexpr int EPI = 256 / EPT;   // edges per iteration (32 / 64)
    constexpr int STR = FOUT + 1;    // padded LDS stride (bank spread)
    __shared__ float agg[128 * STR];
    __shared__ float sb[FOUT];
    const unsigned short* h = (const unsigned short*)h_;
    int b = blockIdx.x, tid = threadIdx.x;
    for (int i = tid; i < 128 * STR; i += 256) agg[i] = 0.0f;
    if (tid < FOUT) sb[tid] = bias[tid];
    __syncthreads();
    uint32_t start = base[b], end = base[b + 1];
    int el = tid / EPT, fl = tid % EPT;
    for (uint32_t e = start + el; e < end; e += EPI) {
        int2 sd = part[e];
        if (sd.x < sThresh) {
            float nm = dinv[sd.x];
            uint2 hv = *(const uint2*)(h + sd.x * FOUT + fl * 4);
            float* ap = &agg[(sd.y & 127) * STR + fl * 4];
            atomicAdd(ap + 0, nm * b2f(hv.x & 0xffffu));
            atomicAdd(ap + 1, nm * b2f(hv.x >> 16));
            atomicAdd(ap + 2, nm * b2f(hv.y & 0xffffu));
            atomicAdd(ap + 3, nm * b2f(hv.y >> 16));
        }
    }
    if (pads) {  // stage-2/3 pad edges: (n-1 -> node 0) and (0 -> node n-1)
        if (b == 0 && tid < EPT) {
            float nm = dinv[n - 1];
            uint2 hv = *(const uint2*)(h + (size_t)(n - 1) * FOUT + tid * 4);
            float* ap = &agg[0 * STR + tid * 4];
            atomicAdd(ap + 0, nm * b2f(hv.x & 0xffffu));
            atomicAdd(ap + 1, nm * b2f(hv.x >> 16));
            atomicAdd(ap + 2, nm * b2f(hv.y & 0xffffu));
            atomicAdd(ap + 3, nm * b2f(hv.y >> 16));
        }
        if (b == (int)gridDim.x - 1 && tid >= 64 && tid < 64 + EPT) {
            int f2 = tid - 64;
            float nm = dinv[0];
            uint2 hv = *(const uint2*)(h + f2 * 4);
            float* ap = &agg[127 * STR + f2 * 4];
            atomicAdd(ap + 0, nm * b2f(hv.x & 0xffffu));
            atomicAdd(ap + 1, nm * b2f(hv.x >> 16));
            atomicAdd(ap + 2, nm * b2f(hv.y & 0xffffu));
            atomicAdd(ap + 3, nm * b2f(hv.y >> 16));
        }
    }
    __syncthreads();
    // epilogue: pooled[i] = relu(max(node 2i, node 2i+1)), 64 rows per bucket
    for (int idx = tid; idx < 64 * FOUT; idx += 256) {
        int i = idx / FOUT, f = idx % FOUT;
        int g0 = b * 128 + 2 * i;
        float d0 = dinv[g0], d1 = dinv[g0 + 1];
        float h0 = b2f(h[g0 * FOUT + f]);
        float h1 = b2f(h[(g0 + 1) * FOUT + f]);
        float v0 = d0 * agg[(2 * i) * STR + f] + d0 * d0 * h0 + sb[f];
        float v1 = d1 * agg[(2 * i + 1) * STR + f] + d1 * d1 * h1 + sb[f];
        float r = fmaxf(fmaxf(v0, v1), 0.0f);
        if constexpr (OUT_BF16)
            ((bf16*)outp)[(b * 64 + i) * FOUT + f] = __float2bfloat16(r);
        else
            ((float*)outp)[(b * 64 + i) * FOUT + f] = r;
    }
}

// ---------------------------------------------------------------------------
// Workspace layout (63 MiB peak, proven available in r6):
//   @0    : part int2 (32 MiB, alive all stages)
//   @32   : counts/pref u32 [512][2048] (4 MiB)
//   @36   : base u32[2049] (8 KiB+4)   @36+16K: tot u32[2048] (8 KiB)
//   @37   : dinv1 f32 (1 MiB)  @38: dinv2 (512 KiB)  @38.5: dinv3 (256 KiB)
//   @39   : h1 bf16 16 MiB -> h2 8 MiB -> h3 2 MiB (sequential reuse)
//   @55   : pool1 bf16 8 MiB -> pool2 bf16 4 MiB
// ---------------------------------------------------------------------------
extern "C" void kernel_launch(void* const* d_in, const int* in_sizes, int n_in,
                              void* d_out, int out_size, void* d_ws, size_t ws_size,
                              hipStream_t stream) {
    const float* x  = (const float*)d_in[0];
    const int*   ei = (const int*)d_in[1];
    const float* W1 = (const float*)d_in[2];
    const float* b1 = (const float*)d_in[3];
    const float* W2 = (const float*)d_in[4];
    const float* b2 = (const float*)d_in[5];
    const float* W3 = (const float*)d_in[6];
    const float* b3 = (const float*)d_in[7];
    float* out = (float*)d_out;

    char* ws = (char*)d_ws;
    int2*     part   = (int2*)ws;
    uint32_t* counts = (uint32_t*)(ws + (32u << 20));
    uint32_t* basep  = (uint32_t*)(ws + (36u << 20));
    uint32_t* tot    = (uint32_t*)(ws + (36u << 20) + (16u << 10));
    float*    dinv1  = (float*)(ws + (37u << 20));
    float*    dinv2  = (float*)(ws + (38u << 20));
    float*    dinv3  = (float*)(ws + (38u << 20) + (512u << 10));
    bf16*     h1     = (bf16*)(ws + (39u << 20));
    bf16*     h2     = h1;
    bf16*     h3     = h1;
    bf16*     pool1  = (bf16*)(ws + (55u << 20));
    bf16*     pool2  = pool1;

    // partition build + edge outputs (no global atomics anywhere)
    hist_kernel<<<NCHUNK, 256, 0, stream>>>(ei, out, counts);
    colscan_kernel<<<NBUCK, 256, 0, stream>>>(counts, tot);
    base_kernel<<<1, 256, 0, stream>>>(tot, basep);
    partition_kernel<<<NCHUNK, 256, 0, stream>>>(ei, counts, basep, part);
    degall_kernel<<<NBUCK, 256, 0, stream>>>(part, basep, dinv1, dinv2, dinv3);

    // stage 1: n=262144, 32->32, all edges valid, no pads
    xform_kernel<32, false><<<N_NODES / 8, 256, 0, stream>>>(x, W1, h1);
    agg_kernel<32, true><<<2048, 256, 0, stream>>>(part, basep, dinv1, h1, b1,
                                                   pool1, N_NODES, N_NODES, 0);
    // stage 2: n=131072, 32->32, filter s<131072, pads active
    xform_kernel<32, true><<<131072 / 8, 256, 0, stream>>>(pool1, W2, h2);
    agg_kernel<32, true><<<1024, 256, 0, stream>>>(part, basep, dinv2, h2, b2,
                                                   pool2, 131072, 131072, 1);
    // stage 3: n=65536, 32->16, filter s<65536, pads active -> final output
    xform_kernel<16, true><<<65536 / 16, 256, 0, stream>>>(pool2, W3, h3);
    agg_kernel<16, false><<<512, 256, 0, stream>>>(part, basep, dinv3, h3, b3,
                                                   out, 65536, 65536, 1);
}